// Round 4
// baseline (171.193 us; speedup 1.0000x reference)
//
#include <hip/hip_runtime.h>
#include <hip/hip_bf16.h>

typedef __bf16 bf16x8 __attribute__((ext_vector_type(8)));
typedef float f32x4 __attribute__((ext_vector_type(4)));
typedef unsigned short u16;
typedef u16 u16x8 __attribute__((ext_vector_type(8)));

#define DENSE_RC 0.0441941738f   // 1/sqrt(512)
#define CONV_RC  0.0147313913f   // 1/sqrt(9*512)

__device__ inline u16 f2bf(float v) {
  union { float f; unsigned u; } x; x.f = v;
  unsigned r = x.u + 0x7fffu + ((x.u >> 16) & 1u);   // RNE
  return (u16)(r >> 16);
}

__device__ inline void gload16(const void* g, void* l) {
  __builtin_amdgcn_global_load_lds(
      (const __attribute__((address_space(1))) unsigned int*)g,
      (__attribute__((address_space(3))) unsigned int*)l, 16, 0, 0);
}

// ---------- 1. style: s[b][i] = DENSE_RC * (y[b] . w_mod[:,i]) + b_mod[i] + 1
__global__ void style_k(const float* __restrict__ y, const float* __restrict__ wm,
                        const float* __restrict__ bm, float* __restrict__ s) {
  const int tid = threadIdx.x, lane = tid & 63, wv = tid >> 6;
  const int idx = blockIdx.x * 64 + lane;
  const int b = idx >> 9, i = idx & 511;
  const float* yb = y + b * 512;
  float acc = 0.f;
  const int j0 = wv * 128;
#pragma unroll 8
  for (int j = j0; j < j0 + 128; ++j) acc += yb[j] * wm[j * 512 + i];
  __shared__ float red[4][64];
  red[wv][lane] = acc;
  __syncthreads();
  if (wv == 0) {
    float a = red[0][lane] + red[1][lane] + red[2][lane] + red[3][lane];
    s[idx] = a * DENSE_RC + bm[i] + 1.0f;
  }
}

// ---------- 2. wsq[i][o] = sum_t w[t][i][o]^2
__global__ void wsq_k(const float* __restrict__ w, float* __restrict__ wsq) {
  const int idx = blockIdx.x * 256 + threadIdx.x;   // i*512+o
  float a = 0.f;
#pragma unroll
  for (int t = 0; t < 9; ++t) { float v = w[(size_t)t * 262144 + idx]; a += v * v; }
  wsq[idx] = a;
}

// ---------- 3. d[b][o] = rsqrt(CONV_RC^2 * sum_i s^2 * wsq + 1e-8)
__global__ void demod_k(const float* __restrict__ s, const float* __restrict__ wsq,
                        float* __restrict__ dmd) {
  const int tid = threadIdx.x, lane = tid & 63, wv = tid >> 6;
  const int idx = blockIdx.x * 64 + lane;
  const int b = idx >> 9, o = idx & 511;
  const float* sb = s + b * 512;
  float a = 0.f;
  const int i0 = wv * 128;
#pragma unroll 4
  for (int i = i0; i < i0 + 128; ++i) { float sv = sb[i]; a += sv * sv * wsq[i * 512 + o]; }
  __shared__ float red[4][64];
  red[wv][lane] = a;
  __syncthreads();
  if (wv == 0) {
    float t = red[0][lane] + red[1][lane] + red[2][lane] + red[3][lane];
    dmd[idx] = rsqrtf(t * (CONV_RC * CONV_RC) + 1e-8f);
  }
}

// ---------- 4. ww[b][t][o][i] = bf16( w[t][i][o] * CONV_RC * s[b][i] * d[b][o] )
__global__ void modw_k(const float* __restrict__ w, const float* __restrict__ s,
                       const float* __restrict__ dmd, u16* __restrict__ wwb) {
  const int blk = blockIdx.x;               // 9*16*8 = 1152
  const int ob = blk & 7, ib = (blk >> 3) & 15, t = blk >> 7;
  __shared__ float lw[32][65];
  const int tid = threadIdx.x;
#pragma unroll
  for (int k = 0; k < 8; ++k) {
    const int e = tid + k * 256;
    const int i = e >> 6, o = e & 63;
    lw[i][o] = w[(size_t)t * 262144 + (size_t)(ib * 32 + i) * 512 + ob * 64 + o];
  }
  __syncthreads();
  const int oo = tid >> 2, q = tid & 3;
  const int ii0 = q * 8;
  for (int b = 0; b < 8; ++b) {
    const float f = CONV_RC * dmd[b * 512 + ob * 64 + oo];
    u16x8 pk;
#pragma unroll
    for (int j = 0; j < 8; ++j)
      pk[j] = f2bf(lw[ii0 + j][oo] * s[b * 512 + ib * 32 + ii0 + j] * f);
    *(u16x8*)(wwb + ((size_t)(b * 9 + t) * 512 + ob * 64 + oo) * 512 + ib * 32 + ii0) = pk;
  }
}

// ---------- 5a. zero only the 1-px border ring of xpad
__global__ void border_k(u16* __restrict__ xpad) {
  const int idx = blockIdx.x * 256 + threadIdx.x;   // 520*256 = 133120 exact
  const int chunk = idx & 63;
  const int p = (idx >> 6) % 260;
  const int b = idx / (260 * 64);
  int row, col;
  if (p < 66)       { row = 0;       col = p; }
  else if (p < 132) { row = 65;      col = p - 66; }
  else if (p < 196) { row = p - 131; col = 0; }
  else              { row = p - 195; col = 65; }
  u16x8 z = {0, 0, 0, 0, 0, 0, 0, 0};
  *(u16x8*)(xpad + ((size_t)(b * 66 + row) * 66 + col) * 512 + chunk * 8) = z;
}

// ---------- 5b. xpad[b][h+1][wcol+1][i] = bf16(x[b][i][h][wcol])   (NCHW -> padded NHWC)
__global__ void fill_k(const float* __restrict__ x, u16* __restrict__ xpad) {
  const int blk = blockIdx.x;               // 8*64*4 = 2048
  const int ib = blk & 3, hh = (blk >> 2) & 63, b = blk >> 8;
  __shared__ float lx[128][65];
  const int tid = threadIdx.x;
#pragma unroll
  for (int k = 0; k < 2; ++k) {
    const int u = tid + k * 256;
    const int i = u >> 2, w0 = (u & 3) * 16;
    const float* src = x + (size_t)((b * 512 + ib * 128 + i) * 64 + hh) * 64 + w0;
    float tmp[16];
    ((float4*)tmp)[0] = ((const float4*)src)[0];
    ((float4*)tmp)[1] = ((const float4*)src)[1];
    ((float4*)tmp)[2] = ((const float4*)src)[2];
    ((float4*)tmp)[3] = ((const float4*)src)[3];
#pragma unroll
    for (int j = 0; j < 16; ++j) lx[i][w0 + j] = tmp[j];
  }
  __syncthreads();
  const int c = tid >> 2, q = tid & 3;
  const size_t base = ((size_t)(b * 66 + hh + 1) * 66 + (c + 1)) * 512 + ib * 128;
#pragma unroll
  for (int k = 0; k < 4; ++k) {
    const int irow = k * 32 + q * 8;
    u16x8 pk;
#pragma unroll
    for (int j = 0; j < 8; ++j) pk[j] = f2bf(lx[irow + j][c]);
    *(u16x8*)(xpad + base + irow) = pk;
  }
}

// ---------- 6. conv, pingpong double-buffered (T3 minimum 2-phase)
// block: 64 o x [8 rows x 64 px], 4 waves; wave = 64o x 128px
// Per buffer: WS [9][64][32] (36864B) + XS [10][66][32] (42240B) = 79104B, stride 79872.
// Two buffers = 159744B -> 1 block/CU. Per kb: issue next-buffer global_load_lds FIRST,
// then 9-tap MFMA on current buffer, then ONE vmcnt(0)+barrier. Loads overlap compute.
// 16B-chunk XOR swizzle per region (involution, source-side pre-swizzled).
__global__ __launch_bounds__(256, 1) void conv_k(const u16* __restrict__ xpad,
                                                 const u16* __restrict__ wwb,
                                                 float* __restrict__ out) {
  __shared__ __align__(1024) char SM[159744];
  int blk = (int)blockIdx.x;
  blk = ((blk & 7) << 6) | (blk >> 3);      // XCD swizzle (512 % 8 == 0, bijective)
  const int pt = blk & 7, ot = (blk >> 3) & 7, b = blk >> 6;
  const int tid = threadIdx.x;
  const int lane = tid & 63, wv = tid >> 6;
  const int rA = lane >> 4, cA = lane & 15;
  const int h0 = pt * 8;

  const size_t wwbase = (size_t)(b * 9) * 262144 + (size_t)ot * 64 * 512;
  const size_t xbase  = (size_t)(b * 66 + h0) * (66 * 512);

  // per-thread staging source pointers; lc = tidswz + r*256 -> uniform per-r strides
  const int tidswz = tid ^ ((tid >> 3) & 3);
  const u16* aw[9];
  const u16* ax[11];
#pragma unroll
  for (int r = 0; r < 9; ++r)
    aw[r] = wwb + wwbase + (size_t)r * 262144 + ((tidswz >> 2) & 63) * 512 + (tidswz & 3) * 8;
#pragma unroll
  for (int r = 0; r < 11; ++r)
    ax[r] = xpad + xbase + (size_t)((tidswz >> 2) + r * 64) * 512 + (tidswz & 3) * 8;
  const bool extra = (tid < 80);                  // 2640 XS chunks = 10*256 + 80

  auto stage = [&](int ofs) {
#pragma unroll
    for (int r = 0; r < 9; ++r)
      gload16(aw[r], SM + ofs + tid * 16 + r * 4096);
#pragma unroll
    for (int r = 0; r < 10; ++r)
      gload16(ax[r], SM + ofs + 36864 + tid * 16 + r * 4096);
    if (extra) gload16(ax[10], SM + ofs + 36864 + tid * 16 + 40960);
#pragma unroll
    for (int r = 0; r < 9; ++r) aw[r] += 32;      // +64B: next i-chunk
#pragma unroll
    for (int r = 0; r < 11; ++r) ax[r] += 32;
  };

  f32x4 acc[4][8];
#pragma unroll
  for (int i = 0; i < 4; ++i)
#pragma unroll
    for (int j = 0; j < 8; ++j) acc[i][j] = (f32x4){0.f, 0.f, 0.f, 0.f};

  const int AbOff = (cA * 64 + rA * 16) ^ ((cA << 3) & 0x30);

  auto compute = [&](int ofs) {
    const char* Ab = SM + ofs + AbOff;
#pragma unroll
    for (int t = 0; t < 9; ++t) {
      const int ty = t / 3, tx = t % 3;
      bf16x8 af[4];
#pragma unroll
      for (int mi = 0; mi < 4; ++mi)
        af[mi] = *(const bf16x8*)(Ab + t * 4096 + mi * 1024);
#pragma unroll
      for (int hf = 0; hf < 2; ++hf) {
        const int rct = (2 * wv + ty + hf) * 66 + cA + tx;
        const char* Bt = SM + ofs + 36864 + ((rct * 64 + rA * 16) ^ ((rct << 3) & 0x30));
        bf16x8 bfr[4];
#pragma unroll
        for (int n = 0; n < 4; ++n)
          bfr[n] = *(const bf16x8*)(Bt + n * 1024);
#pragma unroll
        for (int mi = 0; mi < 4; ++mi)
#pragma unroll
          for (int n = 0; n < 4; ++n)
            acc[mi][hf * 4 + n] = __builtin_amdgcn_mfma_f32_16x16x32_bf16(
                af[mi], bfr[n], acc[mi][hf * 4 + n], 0, 0, 0);
      }
    }
  };

  // prologue: stage kb=0 into buf0
  stage(0);
  asm volatile("s_waitcnt vmcnt(0)" ::: "memory");
  __syncthreads();

  int cofs = 0, nofs = 79872;
  for (int kb = 0; kb < 15; ++kb) {
    stage(nofs);                 // prefetch kb+1 — flies during compute
    compute(cofs);
    asm volatile("s_waitcnt vmcnt(0)" ::: "memory");
    __syncthreads();
    const int t = cofs; cofs = nofs; nofs = t;
  }
  compute(cofs);                 // last kb, no prefetch

  const int hb = h0 + 2 * wv;
#pragma unroll
  for (int mi = 0; mi < 4; ++mi)
#pragma unroll
    for (int ni = 0; ni < 8; ++ni) {
      const int h = hb + (ni >> 2);
      const int wc = (ni & 3) * 16 + cA;
#pragma unroll
      for (int r = 0; r < 4; ++r) {
        const int o = ot * 64 + mi * 16 + rA * 4 + r;
        out[((size_t)(b * 512 + o) * 64 + h) * 64 + wc] = acc[mi][ni][r];
      }
    }
}

extern "C" void kernel_launch(void* const* d_in, const int* in_sizes, int n_in,
                              void* d_out, int out_size, void* d_ws, size_t ws_size,
                              hipStream_t stream) {
  const float* x     = (const float*)d_in[0];   // [8,512,64,64]
  const float* y     = (const float*)d_in[1];   // [8,512]
  const float* w     = (const float*)d_in[2];   // [3,3,512,512]
  const float* w_mod = (const float*)d_in[3];   // [512,512]
  const float* b_mod = (const float*)d_in[4];   // [512]
  float* out = (float*)d_out;

  char* ws = (char*)d_ws;
  float* s    = (float*)(ws);                               // 16 KB
  float* dmd  = (float*)(ws + 16384);                       // 16 KB
  float* wsq  = (float*)(ws + 32768);                       // 1 MB
  u16*   wwb  = (u16*)(ws + 32768 + 1048576);               // 37,748,736 B
  u16*   xpad = (u16*)(ws + 32768 + 1048576 + 37748736);    // 35,684,352 B

  style_k<<<64, 256, 0, stream>>>(y, w_mod, b_mod, s);
  wsq_k<<<1024, 256, 0, stream>>>(w, wsq);
  demod_k<<<64, 256, 0, stream>>>(s, wsq, dmd);
  modw_k<<<1152, 256, 0, stream>>>(w, s, dmd, wwb);
  border_k<<<520, 256, 0, stream>>>(xpad);
  fill_k<<<2048, 256, 0, stream>>>(x, xpad);
  conv_k<<<512, 256, 0, stream>>>(xpad, wwb, out);
}

// Round 5
// 167.147 us; speedup vs baseline: 1.0242x; 1.0242x over previous
//
#include <hip/hip_runtime.h>
#include <hip/hip_bf16.h>

typedef __bf16 bf16x8 __attribute__((ext_vector_type(8)));
typedef float f32x4 __attribute__((ext_vector_type(4)));
typedef unsigned short u16;
typedef u16 u16x8 __attribute__((ext_vector_type(8)));

#define DENSE_RC 0.0441941738f   // 1/sqrt(512)
#define CONV_RC  0.0147313913f   // 1/sqrt(9*512)

__device__ inline u16 f2bf(float v) {
  union { float f; unsigned u; } x; x.f = v;
  unsigned r = x.u + 0x7fffu + ((x.u >> 16) & 1u);   // RNE
  return (u16)(r >> 16);
}

__device__ inline void gload16(const void* g, void* l) {
  __builtin_amdgcn_global_load_lds(
      (const __attribute__((address_space(1))) unsigned int*)g,
      (__attribute__((address_space(3))) unsigned int*)l, 16, 0, 0);
}

// ---------- 1. style: s[b][i] = DENSE_RC * (y[b] . w_mod[:,i]) + b_mod[i] + 1
__global__ void style_k(const float* __restrict__ y, const float* __restrict__ wm,
                        const float* __restrict__ bm, float* __restrict__ s) {
  const int tid = threadIdx.x, lane = tid & 63, wv = tid >> 6;
  const int idx = blockIdx.x * 64 + lane;
  const int b = idx >> 9, i = idx & 511;
  const float* yb = y + b * 512;
  float acc = 0.f;
  const int j0 = wv * 128;
#pragma unroll 8
  for (int j = j0; j < j0 + 128; ++j) acc += yb[j] * wm[j * 512 + i];
  __shared__ float red[4][64];
  red[wv][lane] = acc;
  __syncthreads();
  if (wv == 0) {
    float a = red[0][lane] + red[1][lane] + red[2][lane] + red[3][lane];
    s[idx] = a * DENSE_RC + bm[i] + 1.0f;
  }
}

// ---------- 2. wsq[i][o] = sum_t w[t][i][o]^2
__global__ void wsq_k(const float* __restrict__ w, float* __restrict__ wsq) {
  const int idx = blockIdx.x * 256 + threadIdx.x;   // i*512+o
  float a = 0.f;
#pragma unroll
  for (int t = 0; t < 9; ++t) { float v = w[(size_t)t * 262144 + idx]; a += v * v; }
  wsq[idx] = a;
}

// ---------- 3. d[b][o] = rsqrt(CONV_RC^2 * sum_i s^2 * wsq + 1e-8)
__global__ void demod_k(const float* __restrict__ s, const float* __restrict__ wsq,
                        float* __restrict__ dmd) {
  const int tid = threadIdx.x, lane = tid & 63, wv = tid >> 6;
  const int idx = blockIdx.x * 64 + lane;
  const int b = idx >> 9, o = idx & 511;
  const float* sb = s + b * 512;
  float a = 0.f;
  const int i0 = wv * 128;
#pragma unroll 4
  for (int i = i0; i < i0 + 128; ++i) { float sv = sb[i]; a += sv * sv * wsq[i * 512 + o]; }
  __shared__ float red[4][64];
  red[wv][lane] = a;
  __syncthreads();
  if (wv == 0) {
    float t = red[0][lane] + red[1][lane] + red[2][lane] + red[3][lane];
    dmd[idx] = rsqrtf(t * (CONV_RC * CONV_RC) + 1e-8f);
  }
}

// ---------- 4. ww[b][t][o][i] = bf16( w[t][i][o] * CONV_RC * s[b][i] * d[b][o] )
__global__ void modw_k(const float* __restrict__ w, const float* __restrict__ s,
                       const float* __restrict__ dmd, u16* __restrict__ wwb) {
  const int blk = blockIdx.x;               // 9*16*8 = 1152
  const int ob = blk & 7, ib = (blk >> 3) & 15, t = blk >> 7;
  __shared__ float lw[32][65];
  const int tid = threadIdx.x;
#pragma unroll
  for (int k = 0; k < 8; ++k) {
    const int e = tid + k * 256;
    const int i = e >> 6, o = e & 63;
    lw[i][o] = w[(size_t)t * 262144 + (size_t)(ib * 32 + i) * 512 + ob * 64 + o];
  }
  __syncthreads();
  const int oo = tid >> 2, q = tid & 3;
  const int ii0 = q * 8;
  for (int b = 0; b < 8; ++b) {
    const float f = CONV_RC * dmd[b * 512 + ob * 64 + oo];
    u16x8 pk;
#pragma unroll
    for (int j = 0; j < 8; ++j)
      pk[j] = f2bf(lw[ii0 + j][oo] * s[b * 512 + ib * 32 + ii0 + j] * f);
    *(u16x8*)(wwb + ((size_t)(b * 9 + t) * 512 + ob * 64 + oo) * 512 + ib * 32 + ii0) = pk;
  }
}

// ---------- 5a. zero only the 1-px border ring of xpad
__global__ void border_k(u16* __restrict__ xpad) {
  const int idx = blockIdx.x * 256 + threadIdx.x;   // 520*256 = 133120 exact
  const int chunk = idx & 63;
  const int p = (idx >> 6) % 260;
  const int b = idx / (260 * 64);
  int row, col;
  if (p < 66)       { row = 0;       col = p; }
  else if (p < 132) { row = 65;      col = p - 66; }
  else if (p < 196) { row = p - 131; col = 0; }
  else              { row = p - 195; col = 65; }
  u16x8 z = {0, 0, 0, 0, 0, 0, 0, 0};
  *(u16x8*)(xpad + ((size_t)(b * 66 + row) * 66 + col) * 512 + chunk * 8) = z;
}

// ---------- 5b. xpad[b][h+1][wcol+1][i] = bf16(x[b][i][h][wcol])   (NCHW -> padded NHWC)
__global__ void fill_k(const float* __restrict__ x, u16* __restrict__ xpad) {
  const int blk = blockIdx.x;               // 8*64*4 = 2048
  const int ib = blk & 3, hh = (blk >> 2) & 63, b = blk >> 8;
  __shared__ float lx[128][65];
  const int tid = threadIdx.x;
#pragma unroll
  for (int k = 0; k < 2; ++k) {
    const int u = tid + k * 256;
    const int i = u >> 2, w0 = (u & 3) * 16;
    const float* src = x + (size_t)((b * 512 + ib * 128 + i) * 64 + hh) * 64 + w0;
    float tmp[16];
    ((float4*)tmp)[0] = ((const float4*)src)[0];
    ((float4*)tmp)[1] = ((const float4*)src)[1];
    ((float4*)tmp)[2] = ((const float4*)src)[2];
    ((float4*)tmp)[3] = ((const float4*)src)[3];
#pragma unroll
    for (int j = 0; j < 16; ++j) lx[i][w0 + j] = tmp[j];
  }
  __syncthreads();
  const int c = tid >> 2, q = tid & 3;
  const size_t base = ((size_t)(b * 66 + hh + 1) * 66 + (c + 1)) * 512 + ib * 128;
#pragma unroll
  for (int k = 0; k < 4; ++k) {
    const int irow = k * 32 + q * 8;
    u16x8 pk;
#pragma unroll
    for (int j = 0; j < 8; ++j) pk[j] = f2bf(lx[irow + j][c]);
    *(u16x8*)(xpad + base + irow) = pk;
  }
}

// ---------- 6. conv: out[b][o][h][w] = sum_{t,i} xpad[b][h+ty][w+tx][i] * ww[b][t][o][i]
// block: 128 o x [8 rows x 64 px], 512 thr = 8 waves (2/SIMD); wave = 64o x 128px (2 rows).
// Single buffer: WS [9 t][128 o][32 i] 73728B + XS [10 r][66 c][32 i] 42240B = 115968B
// -> 1 block/CU, grid = 256 (8b x 4ot x 8pt). Serial stage amortized over 2304 MFMA/kb.
// 16B-chunk XOR swizzle per region: phys = log ^ ((log>>3)&3) (involution), source-side
// pre-swizzled for global_load_lds (linear dest), read-side same XOR. 0 conflicts (r2/r3).
// blkIdx = pt*32 + b*4 + ot: the 8 pt-blocks sharing a ww panel land on ONE XCD's L2.
__global__ __launch_bounds__(512, 2) void conv_k(const u16* __restrict__ xpad,
                                                 const u16* __restrict__ wwb,
                                                 float* __restrict__ out) {
  __shared__ __align__(1024) char SM[115968];
  const int blk = (int)blockIdx.x;          // 256
  const int pt = blk >> 5, b = (blk >> 2) & 7, ot = blk & 3;
  const int tid = threadIdx.x;
  const int lane = tid & 63, wv = tid >> 6;
  const int rA = lane >> 4, cA = lane & 15;
  const int wo = wv & 1, wr = wv >> 1;      // o-half, row-pair
  const int h0 = pt * 8;

  const size_t wwbase = (size_t)b * 9 * 262144 + (size_t)ot * 65536;  // ot*128*512
  const size_t xbase  = (size_t)(b * 66 + h0) * (66 * 512);

  // staging source bases (source-side swizzle); advance +32 elems (64B) per kb
  const int tidswz = tid ^ ((tid >> 3) & 3);
  const u16* awb = wwb + wwbase + (tidswz >> 2) * 512 + (tidswz & 3) * 8;
  const u16* axb = xpad + xbase + (size_t)(tidswz >> 2) * 512 + (tidswz & 3) * 8;
  const bool extra = (tid < 80);            // XS chunks 2640 = 5*512 + 80

  f32x4 acc[4][8];
#pragma unroll
  for (int i = 0; i < 4; ++i)
#pragma unroll
    for (int j = 0; j < 8; ++j) acc[i][j] = (f32x4){0.f, 0.f, 0.f, 0.f};

  // A-frag base: chunk = t*512 + o*4 + i8, o = wo*64+mi*16+cA, i8 = rA
  // XOR bits ((chunk>>3)&3)<<4 = ((cA>>1)&3)<<4 : lane-constant (mi*16, wo*64 don't touch)
  const int AbO = ((wo * 4096 + cA * 64 + rA * 16) ^ (((cA >> 1) & 3) << 4));

  for (int kb = 0; kb < 16; ++kb) {
    // ---- stage (serial, amortized): 9 WS rounds (t=r) + 5 XS rounds + 80 extra
#pragma unroll
    for (int r = 0; r < 9; ++r)
      gload16(awb + (size_t)r * 262144, SM + tid * 16 + r * 8192);
#pragma unroll
    for (int r = 0; r < 5; ++r)
      gload16(axb + (size_t)r * 65536, SM + 73728 + tid * 16 + r * 8192);
    if (extra) gload16(axb + 5 * 65536, SM + 73728 + tid * 16 + 40960);
    awb += 32; axb += 32;
    asm volatile("s_waitcnt vmcnt(0)" ::: "memory");
    __syncthreads();

    // ---- compute 9 taps
#pragma unroll
    for (int t = 0; t < 9; ++t) {
      const int ty = t / 3, tx = t % 3;
      bf16x8 af[4];
#pragma unroll
      for (int mi = 0; mi < 4; ++mi)
        af[mi] = *(const bf16x8*)(SM + AbO + t * 8192 + mi * 1024);
#pragma unroll
      for (int hf = 0; hf < 2; ++hf) {
        const int rct = (2 * wr + ty + hf) * 66 + tx + cA;
        const char* Bt = SM + 73728 + ((rct * 64 + rA * 16) ^ (((rct >> 1) & 3) << 4));
        bf16x8 bfr[4];
#pragma unroll
        for (int n = 0; n < 4; ++n)
          bfr[n] = *(const bf16x8*)(Bt + n * 1024);   // +16 cols: swz bits untouched
#pragma unroll
        for (int mi = 0; mi < 4; ++mi)
#pragma unroll
          for (int n = 0; n < 4; ++n)
            acc[mi][hf * 4 + n] = __builtin_amdgcn_mfma_f32_16x16x32_bf16(
                af[mi], bfr[n], acc[mi][hf * 4 + n], 0, 0, 0);
      }
    }
    __syncthreads();
  }

  const int hb = h0 + 2 * wr;
#pragma unroll
  for (int mi = 0; mi < 4; ++mi)
#pragma unroll
    for (int ni = 0; ni < 8; ++ni) {
      const int h = hb + (ni >> 2);
      const int wc = (ni & 3) * 16 + cA;
#pragma unroll
      for (int r = 0; r < 4; ++r) {
        const int o = ot * 128 + wo * 64 + mi * 16 + rA * 4 + r;
        out[((size_t)(b * 512 + o) * 64 + h) * 64 + wc] = acc[mi][ni][r];
      }
    }
}

extern "C" void kernel_launch(void* const* d_in, const int* in_sizes, int n_in,
                              void* d_out, int out_size, void* d_ws, size_t ws_size,
                              hipStream_t stream) {
  const float* x     = (const float*)d_in[0];   // [8,512,64,64]
  const float* y     = (const float*)d_in[1];   // [8,512]
  const float* w     = (const float*)d_in[2];   // [3,3,512,512]
  const float* w_mod = (const float*)d_in[3];   // [512,512]
  const float* b_mod = (const float*)d_in[4];   // [512]
  float* out = (float*)d_out;

  char* ws = (char*)d_ws;
  float* s    = (float*)(ws);                               // 16 KB
  float* dmd  = (float*)(ws + 16384);                       // 16 KB
  float* wsq  = (float*)(ws + 32768);                       // 1 MB
  u16*   wwb  = (u16*)(ws + 32768 + 1048576);               // 37,748,736 B
  u16*   xpad = (u16*)(ws + 32768 + 1048576 + 37748736);    // 35,684,352 B

  style_k<<<64, 256, 0, stream>>>(y, w_mod, b_mod, s);
  wsq_k<<<1024, 256, 0, stream>>>(w, wsq);
  demod_k<<<64, 256, 0, stream>>>(s, wsq, dmd);
  modw_k<<<1152, 256, 0, stream>>>(w, s, dmd, wwb);
  border_k<<<520, 256, 0, stream>>>(xpad);
  fill_k<<<2048, 256, 0, stream>>>(x, xpad);
  conv_k<<<256, 512, 0, stream>>>(xpad, wwb, out);
}